// Round 1
// baseline (65.046 us; speedup 1.0000x reference)
//
#include <hip/hip_runtime.h>

#define B_ 512
#define I_ 256
#define O_ 256
#define K_ 8

static constexpr float NORM_F   = 0.7978845608028654f;   // 1/(0.5*sqrt(2*pi))
static constexpr float LOG2E_F  = 1.4426950408889634f;
static constexpr float NEG2LOG2E = -2.8853900817779268f; // exp(-2 d^2) = exp2(NEG2LOG2E * d^2)

__global__ __launch_bounds__(256) void silu_kernel(const float* __restrict__ x,
                                                   float* __restrict__ si, int n) {
    int idx = blockIdx.x * blockDim.x + threadIdx.x;
    if (idx < n) {
        float v = x[idx];
        float e = __builtin_amdgcn_exp2f(-v * LOG2E_F);   // e^{-v}
        si[idx] = v * __builtin_amdgcn_rcpf(1.0f + e);    // v * sigmoid(v)
    }
}

// One block: 256 threads (thread = o), handles B_TILE batch rows and I_/chunks i's.
// dst layout: [chunk][b][o]  (when chunks==1 this is exactly the output layout)
template <int BT>
__global__ __launch_bounds__(256) void kan_main(const float* __restrict__ x,
                                                const float* __restrict__ cp,
                                                const float* __restrict__ cf,
                                                const float* __restrict__ w,
                                                const float* __restrict__ si,  // may be null
                                                float* __restrict__ dst,
                                                int iN) {
    const int o  = threadIdx.x;
    const int b0 = blockIdx.x * BT;
    const int ic = blockIdx.y;
    const int i0 = ic * iN;

    float acc[BT];
#pragma unroll
    for (int b = 0; b < BT; ++b) acc[b] = 0.0f;

    for (int i = i0; i < i0 + iN; ++i) {
        const int io = i * O_ + o;
        const float4 c0 = reinterpret_cast<const float4*>(cp + io * K_)[0];
        const float4 c1 = reinterpret_cast<const float4*>(cp + io * K_)[1];
        const float4 f0 = reinterpret_cast<const float4*>(cf + io * K_)[0];
        const float4 f1 = reinterpret_cast<const float4*>(cf + io * K_)[1];
        const float wv = w[io];
        const float wn = wv * NORM_F;

        float xv[BT], sv[BT];
#pragma unroll
        for (int b = 0; b < BT; ++b) {
            xv[b] = x[(b0 + b) * I_ + i];
            if (si) {
                sv[b] = si[(b0 + b) * I_ + i];
            } else {
                float e = __builtin_amdgcn_exp2f(-xv[b] * LOG2E_F);
                sv[b] = xv[b] * __builtin_amdgcn_rcpf(1.0f + e);
            }
        }

#pragma unroll
        for (int b = 0; b < BT; ++b) {
            const float xb = xv[b];
            float s = 0.0f, d, e;
            d = xb - c0.x; e = __builtin_amdgcn_exp2f(d * d * NEG2LOG2E); s = fmaf(e, f0.x, s);
            d = xb - c0.y; e = __builtin_amdgcn_exp2f(d * d * NEG2LOG2E); s = fmaf(e, f0.y, s);
            d = xb - c0.z; e = __builtin_amdgcn_exp2f(d * d * NEG2LOG2E); s = fmaf(e, f0.z, s);
            d = xb - c0.w; e = __builtin_amdgcn_exp2f(d * d * NEG2LOG2E); s = fmaf(e, f0.w, s);
            d = xb - c1.x; e = __builtin_amdgcn_exp2f(d * d * NEG2LOG2E); s = fmaf(e, f1.x, s);
            d = xb - c1.y; e = __builtin_amdgcn_exp2f(d * d * NEG2LOG2E); s = fmaf(e, f1.y, s);
            d = xb - c1.z; e = __builtin_amdgcn_exp2f(d * d * NEG2LOG2E); s = fmaf(e, f1.z, s);
            d = xb - c1.w; e = __builtin_amdgcn_exp2f(d * d * NEG2LOG2E); s = fmaf(e, f1.w, s);
            acc[b] = fmaf(wv, sv[b], acc[b]);
            acc[b] = fmaf(wn, s, acc[b]);
        }
    }

#pragma unroll
    for (int b = 0; b < BT; ++b)
        dst[(ic * B_ + (b0 + b)) * O_ + o] = acc[b];
}

__global__ __launch_bounds__(256) void reduce_kernel(const float* __restrict__ part,
                                                     float* __restrict__ out, int chunks) {
    const int o = threadIdx.x;
    const int b = blockIdx.x;
    float s = 0.0f;
    for (int c = 0; c < chunks; ++c) s += part[(c * B_ + b) * O_ + o];
    out[b * O_ + o] = s;
}

extern "C" void kernel_launch(void* const* d_in, const int* in_sizes, int n_in,
                              void* d_out, int out_size, void* d_ws, size_t ws_size,
                              hipStream_t stream) {
    const float* x  = (const float*)d_in[0];
    const float* cp = (const float*)d_in[1];
    const float* cf = (const float*)d_in[2];
    const float* w  = (const float*)d_in[3];
    float* out = (float*)d_out;

    constexpr int BT = 8;
    const size_t si_bytes = (size_t)B_ * I_ * sizeof(float);

    // Adapt to workspace size (deterministic given fixed ws_size).
    bool use_si = ws_size >= si_bytes;
    int chunks = 16;
    while (chunks > 1 &&
           (use_si ? si_bytes : 0) + (size_t)chunks * B_ * O_ * sizeof(float) > ws_size)
        chunks >>= 1;
    if ((use_si ? si_bytes : 0) + (size_t)chunks * B_ * O_ * sizeof(float) > ws_size)
        chunks = 1;  // direct-to-out fallback

    float* si   = use_si ? (float*)d_ws : nullptr;
    float* part = use_si ? (float*)d_ws + (size_t)B_ * I_ : (float*)d_ws;

    if (use_si) {
        silu_kernel<<<(B_ * I_ + 255) / 256, 256, 0, stream>>>(x, si, B_ * I_);
    }

    float* dst = (chunks == 1) ? out : part;
    dim3 grid(B_ / BT, chunks);
    kan_main<BT><<<grid, 256, 0, stream>>>(x, cp, cf, w, si, dst, I_ / chunks);

    if (chunks > 1) {
        reduce_kernel<<<B_, 256, 0, stream>>>(part, out, chunks);
    }
}

// Round 2
// 16.670 us; speedup vs baseline: 3.9019x; 3.9019x over previous
//
#include <hip/hip_runtime.h>

#define B_ 512
#define I_ 256
#define O_ 256
#define K_ 8

static constexpr float NORM_F    = 0.7978845608028654f;   // 1/(0.5*sqrt(2*pi))
static constexpr float LOG2E_F   = 1.4426950408889634f;
static constexpr float NEG2LOG2E = -2.8853900817779268f;  // exp(-2 d^2) = exp2(NEG2LOG2E * d^2)

#define GUARD_B 256   // guard grid size; main kernel block size must equal this

// Scan inputs, write per-block {cp_min, cp_max, max|x|, max|cf|, max|w|} to ws.
// No atomics, no init needed -> deterministic, no memset dispatches.
__global__ __launch_bounds__(256) void guard_scan(const float* __restrict__ x,
                                                  const float* __restrict__ cp,
                                                  const float* __restrict__ cf,
                                                  const float* __restrict__ w,
                                                  float* __restrict__ g) {
    const int tid = blockIdx.x * blockDim.x + threadIdx.x;
    const int stride = gridDim.x * blockDim.x;
    float cpmin = 1e30f, cpmax = -1e30f, xm = 0.0f, cfm = 0.0f, wm = 0.0f;
    for (int i = tid; i < B_ * I_; i += stride) xm = fmaxf(xm, fabsf(x[i]));
    for (int i = tid; i < I_ * O_ * K_; i += stride) {
        float v = cp[i];
        cpmin = fminf(cpmin, v);
        cpmax = fmaxf(cpmax, v);
    }
    for (int i = tid; i < I_ * O_ * K_; i += stride) cfm = fmaxf(cfm, fabsf(cf[i]));
    for (int i = tid; i < I_ * O_; i += stride) wm = fmaxf(wm, fabsf(w[i]));

    // wave reduce (64 lanes)
    for (int off = 32; off; off >>= 1) {
        cpmin = fminf(cpmin, __shfl_xor(cpmin, off));
        cpmax = fmaxf(cpmax, __shfl_xor(cpmax, off));
        xm    = fmaxf(xm,    __shfl_xor(xm, off));
        cfm   = fmaxf(cfm,   __shfl_xor(cfm, off));
        wm    = fmaxf(wm,    __shfl_xor(wm, off));
    }
    __shared__ float s[4][5];
    const int wv = threadIdx.x >> 6, ln = threadIdx.x & 63;
    if (ln == 0) { s[wv][0] = cpmin; s[wv][1] = cpmax; s[wv][2] = xm; s[wv][3] = cfm; s[wv][4] = wm; }
    __syncthreads();
    if (threadIdx.x == 0) {
        for (int q = 1; q < 4; ++q) {
            s[0][0] = fminf(s[0][0], s[q][0]);
            s[0][1] = fmaxf(s[0][1], s[q][1]);
            s[0][2] = fmaxf(s[0][2], s[q][2]);
            s[0][3] = fmaxf(s[0][3], s[q][3]);
            s[0][4] = fmaxf(s[0][4], s[q][4]);
        }
        float* p = g + blockIdx.x * 8;
        p[0] = s[0][0]; p[1] = s[0][1]; p[2] = s[0][2]; p[3] = s[0][3]; p[4] = s[0][4];
    }
}

// One block = 256 threads (thread = o), BT batch rows, full I range.
// Reads guard partials; if the spline term is provably < 1e-7, runs the
// GEMM-only fast path; otherwise the full exp path (correct for any input).
template <int BT>
__global__ __launch_bounds__(256) void kan_fused(const float* __restrict__ x,
                                                 const float* __restrict__ cp,
                                                 const float* __restrict__ cf,
                                                 const float* __restrict__ w,
                                                 const float* __restrict__ g,  // may be null
                                                 float* __restrict__ out) {
    const int o  = threadIdx.x;
    const int b0 = blockIdx.x * BT;

    __shared__ float red[4][5];
    __shared__ float si[BT][I_];
    __shared__ float sx[BT][I_];

    // --- reduce guard partials (GUARD_B entries, one per thread) ---
    bool skip = false;
    if (g) {
        const float* p = g + threadIdx.x * 8;
        float cpmin = p[0], cpmax = p[1], xm = p[2], cfm = p[3], wm = p[4];
        for (int off = 32; off; off >>= 1) {
            cpmin = fminf(cpmin, __shfl_xor(cpmin, off));
            cpmax = fmaxf(cpmax, __shfl_xor(cpmax, off));
            xm    = fmaxf(xm,    __shfl_xor(xm, off));
            cfm   = fmaxf(cfm,   __shfl_xor(cfm, off));
            wm    = fmaxf(wm,    __shfl_xor(wm, off));
        }
        const int wv = threadIdx.x >> 6, ln = threadIdx.x & 63;
        if (ln == 0) { red[wv][0] = cpmin; red[wv][1] = cpmax; red[wv][2] = xm; red[wv][3] = cfm; red[wv][4] = wm; }
        __syncthreads();
        cpmin = fminf(fminf(red[0][0], red[1][0]), fminf(red[2][0], red[3][0]));
        cpmax = fmaxf(fmaxf(red[0][1], red[1][1]), fmaxf(red[2][1], red[3][1]));
        xm    = fmaxf(fmaxf(red[0][2], red[1][2]), fmaxf(red[2][2], red[3][2]));
        cfm   = fmaxf(fmaxf(red[0][3], red[1][3]), fmaxf(red[2][3], red[3][3]));
        wm    = fmaxf(fmaxf(red[0][4], red[1][4]), fmaxf(red[2][4], red[3][4]));
        // min distance between [-xm, xm] and [cpmin, cpmax]
        float dist = fmaxf(0.0f, fmaxf(cpmin - xm, -cpmax - xm));
        float bmax = __builtin_amdgcn_exp2f(NEG2LOG2E * dist * dist);  // max basis (pre-NORM)
        float bound = NORM_F * bmax * (float)K_ * (float)I_ * wm * cfm;
        skip = (bound < 1e-7f);   // uniform across grid
    }

    // --- stage x and silu(x) rows in LDS (o doubles as i-index; I_ == O_) ---
#pragma unroll
    for (int b = 0; b < BT; ++b) {
        float v = x[(b0 + b) * I_ + o];
        float e = __builtin_amdgcn_exp2f(-v * LOG2E_F);
        sx[b][o] = v;
        si[b][o] = v * __builtin_amdgcn_rcpf(1.0f + e);
    }
    __syncthreads();

    float acc[BT];
#pragma unroll
    for (int b = 0; b < BT; ++b) acc[b] = 0.0f;

    if (skip) {
        // fast path: out[b,o] = sum_i w[i,o] * silu(x[b,i])
#pragma unroll 8
        for (int i = 0; i < I_; ++i) {
            const float wv = w[i * O_ + o];
#pragma unroll
            for (int b = 0; b < BT; ++b) acc[b] = fmaf(wv, si[b][i], acc[b]);
        }
    } else {
        // full path: includes the Gaussian spline term
        for (int i = 0; i < I_; ++i) {
            const int io = i * O_ + o;
            const float4 c0 = reinterpret_cast<const float4*>(cp + io * K_)[0];
            const float4 c1 = reinterpret_cast<const float4*>(cp + io * K_)[1];
            const float4 f0 = reinterpret_cast<const float4*>(cf + io * K_)[0];
            const float4 f1 = reinterpret_cast<const float4*>(cf + io * K_)[1];
            const float wv = w[io];
            const float wn = wv * NORM_F;
#pragma unroll
            for (int b = 0; b < BT; ++b) {
                const float xb = sx[b][i];
                float s = 0.0f, d, e;
                d = xb - c0.x; e = __builtin_amdgcn_exp2f(d * d * NEG2LOG2E); s = fmaf(e, f0.x, s);
                d = xb - c0.y; e = __builtin_amdgcn_exp2f(d * d * NEG2LOG2E); s = fmaf(e, f0.y, s);
                d = xb - c0.z; e = __builtin_amdgcn_exp2f(d * d * NEG2LOG2E); s = fmaf(e, f0.z, s);
                d = xb - c0.w; e = __builtin_amdgcn_exp2f(d * d * NEG2LOG2E); s = fmaf(e, f0.w, s);
                d = xb - c1.x; e = __builtin_amdgcn_exp2f(d * d * NEG2LOG2E); s = fmaf(e, f1.x, s);
                d = xb - c1.y; e = __builtin_amdgcn_exp2f(d * d * NEG2LOG2E); s = fmaf(e, f1.y, s);
                d = xb - c1.z; e = __builtin_amdgcn_exp2f(d * d * NEG2LOG2E); s = fmaf(e, f1.z, s);
                d = xb - c1.w; e = __builtin_amdgcn_exp2f(d * d * NEG2LOG2E); s = fmaf(e, f1.w, s);
                acc[b] = fmaf(wv, si[b][i], acc[b]);
                acc[b] = fmaf(wn, s, acc[b]);
            }
        }
    }

#pragma unroll
    for (int b = 0; b < BT; ++b)
        out[(b0 + b) * O_ + o] = acc[b];
}

extern "C" void kernel_launch(void* const* d_in, const int* in_sizes, int n_in,
                              void* d_out, int out_size, void* d_ws, size_t ws_size,
                              hipStream_t stream) {
    const float* x  = (const float*)d_in[0];
    const float* cp = (const float*)d_in[1];
    const float* cf = (const float*)d_in[2];
    const float* w  = (const float*)d_in[3];
    float* out = (float*)d_out;

    constexpr int BT = 2;
    const size_t guard_bytes = (size_t)GUARD_B * 8 * sizeof(float);

    float* g = nullptr;
    if (ws_size >= guard_bytes) {
        g = (float*)d_ws;
        guard_scan<<<GUARD_B, 256, 0, stream>>>(x, cp, cf, w, g);
    }
    kan_fused<BT><<<B_ / BT, 256, 0, stream>>>(x, cp, cf, w, g, out);
}